// Round 9
// baseline (1083.604 us; speedup 1.0000x reference)
//
#include <hip/hip_runtime.h>
#include <hip/hip_bf16.h>
#include <cstdint>

#define N_NODES 50000
#define N_EDGES 1600000
#define EE (N_EDGES + N_NODES)
#define BSH 7
#define BSIZE 128
#define NBUCKET ((N_NODES + BSIZE - 1) >> BSH)   // 391
#define CSH 13
#define CAP 8192                                  // pow2 bucket capacity (mean fill 4224)

__device__ __forceinline__ float lrelu(float x, float s) { return x >= 0.f ? x : s * x; }
__device__ __forceinline__ float bflo(uint32_t v) { return __uint_as_float(v << 16); }
__device__ __forceinline__ float bfhi(uint32_t v) { return __uint_as_float(v & 0xFFFF0000u); }
__device__ __forceinline__ uint32_t packbf(float a, float b) {
    uint32_t ua = __float_as_uint(a), ub = __float_as_uint(b);
    ua += 0x7FFF + ((ua >> 16) & 1);
    ub += 0x7FFF + ((ub >> 16) & 1);
    return (ua >> 16) | (ub & 0xFFFF0000u);
}
__device__ __forceinline__ float rdlane(float v, int l) {
    return __uint_as_float(__builtin_amdgcn_readlane(__float_as_uint(v), l));
}

// ---------------- Phase A: bin edges into fixed-capacity buckets ----------------
__global__ __launch_bounds__(256) void kA_bin(const int* __restrict__ src, const int* __restrict__ dst,
                                              int* __restrict__ bcur, uint32_t* __restrict__ binned) {
    __shared__ int lcnt[NBUCKET];
    __shared__ int lbase[NBUCKET];
    const int T = 16;
    const int CHUNK = 256 * T;
    int nchunks = (EE + CHUNK - 1) / CHUNK;
    for (int ch = blockIdx.x; ch < nchunks; ch += gridDim.x) {
        for (int i = threadIdx.x; i < NBUCKET; i += 256) lcnt[i] = 0;
        __syncthreads();
        uint32_t pv[T];
        uint32_t pm[T];
        int base = ch * CHUNK;
#pragma unroll
        for (int k = 0; k < T; k++) {
            int e = base + k * 256 + threadIdx.x;
            if (e < EE) {
                int s, d;
                if (e < N_EDGES) { s = src[e]; d = dst[e]; } else { s = e - N_EDGES; d = s; }
                int b = d >> BSH;
                int r = atomicAdd(&lcnt[b], 1);
                pv[k] = (uint32_t)s | ((uint32_t)(d & (BSIZE - 1)) << 16);
                pm[k] = (uint32_t)r | ((uint32_t)b << 16);
            }
        }
        __syncthreads();
        for (int i = threadIdx.x; i < NBUCKET; i += 256) {
            int c = lcnt[i];
            if (c) lbase[i] = atomicAdd(&bcur[i], c);
        }
        __syncthreads();
#pragma unroll
        for (int k = 0; k < T; k++) {
            int e = base + k * 256 + threadIdx.x;
            if (e < EE) {
                int b = pm[k] >> 16, r = pm[k] & 0xFFFF;
                binned[((size_t)b << CSH) + lbase[b] + r] = pv[k];
            }
        }
        __syncthreads();
    }
}

// ---------------- Layer 1: h1 (packed bf16) = x@W1, alpha dot products ----------------
__global__ __launch_bounds__(256) void k_gemm1(
    const float* __restrict__ x, const float* __restrict__ W1,
    const float* __restrict__ as_w, const float* __restrict__ ad_w,
    uint32_t* __restrict__ h1b, float* __restrict__ as1, float* __restrict__ ad1) {
    int c = threadIdx.x & 63;
    int wv = threadIdx.x >> 6;
    float wreg[64];
#pragma unroll
    for (int k = 0; k < 64; k++) wreg[k] = W1[k * 64 + c];
    float aw = as_w[c];
    float dw = ad_w[c];
    int base = blockIdx.x * 16 + wv * 4;   // 3125 * 16 == 50000 exactly
#pragma unroll
    for (int r = 0; r < 4; r++) {
        int n = base + r;
        float xr = x[n * 64 + c];
        float a0 = 0.f, a1 = 0.f, a2 = 0.f, a3 = 0.f;
#pragma unroll
        for (int k = 0; k < 64; k += 4) {
            a0 = fmaf(rdlane(xr, k),     wreg[k],     a0);
            a1 = fmaf(rdlane(xr, k + 1), wreg[k + 1], a1);
            a2 = fmaf(rdlane(xr, k + 2), wreg[k + 2], a2);
            a3 = fmaf(rdlane(xr, k + 3), wreg[k + 3], a3);
        }
        float acc = (a0 + a1) + (a2 + a3);
        float other = __shfl_xor(acc, 1, 64);
        if (!(c & 1)) h1b[n * 32 + (c >> 1)] = packbf(acc, other);
        float asv = acc * aw;
        float adv = acc * dw;
#pragma unroll
        for (int off = 1; off < 16; off <<= 1) {
            asv += __shfl_xor(asv, off, 64);
            adv += __shfl_xor(adv, off, 64);
        }
        if ((c & 15) == 0) { as1[n * 4 + (c >> 4)] = asv; ad1[n * 4 + (c >> 4)] = adv; }
    }
}

// ---- Fused layer-1 aggregation: per-bucket LDS accumulators, arrival order, no sort ----
// block = 1024 threads (16 waves), one bucket of 128 dst nodes.
__global__ __launch_bounds__(1024) void k_fused1(
    const int* __restrict__ bcur, const uint32_t* __restrict__ binned,
    const float* __restrict__ as1, const float* __restrict__ ad1,
    const uint32_t* __restrict__ h1b,
    const float* __restrict__ b1, const float* __restrict__ W2,
    const float* __restrict__ as2w, const float* __restrict__ ad2w,
    float* __restrict__ h2, float* __restrict__ as2, float* __restrict__ ad2) {
    __shared__ float acc[BSIZE][65];      // padded: quarter-stride 4 -> <=2-way, free
    __shared__ float dsumS[BSIZE * 4];
    __shared__ float ad1s[BSIZE * 4];
    __shared__ float W2s[64 * 16];
    __shared__ float as2s[BSIZE];
    __shared__ float ad2s2[BSIZE];
    int b = blockIdx.x, tid = threadIdx.x;
    int p0 = b << CSH;
    int L = bcur[b];

    for (int i = tid; i < BSIZE * 65; i += 1024) ((float*)acc)[i] = 0.f;
    for (int i = tid; i < BSIZE * 4; i += 1024) dsumS[i] = 0.f;
    if (tid < BSIZE * 4) {
        int gi = (b << BSH) * 4 + tid;
        ad1s[tid] = (gi < N_NODES * 4) ? ad1[gi] : 0.f;
    }
    if (tid < 1024) W2s[tid] = W2[tid];
    if (tid < BSIZE) { as2s[tid] = 0.f; ad2s2[tid] = 0.f; }
    __syncthreads();

    int lane = tid & 63, wv = tid >> 6;
    int q = lane >> 4, cl = lane & 15;    // quarter q = edge slot; lane covers ch 4cl..4cl+3
    int hc = cl >> 2;
    int off = wv * 4 + q;                 // 0..63 edge slot within a 64-edge block tile
    const uint2* h1b2 = (const uint2*)h1b;

    for (int e0 = 0; e0 < L; e0 += 64) {
        int idx = e0 + off;
        bool pred = idx < L;
        uint32_t ewd = binned[p0 + (pred ? idx : L - 1)];
        int s = (int)(ewd & 0xFFFF);
        int dl = (int)(ewd >> 16);
        float a = as1[s * 4 + hc];
        float d = ad1s[dl * 4 + hc];
        float e = a + d;
        float w = __expf(e >= 0.f ? e : 0.2f * e);
        w = pred ? w : 0.f;
        uint2 v = h1b2[s * 16 + cl];
        atomicAdd(&acc[dl][4 * cl + 0], w * bflo(v.x));
        atomicAdd(&acc[dl][4 * cl + 1], w * bfhi(v.x));
        atomicAdd(&acc[dl][4 * cl + 2], w * bflo(v.y));
        atomicAdd(&acc[dl][4 * cl + 3], w * bfhi(v.y));
        if ((cl & 3) == 0) atomicAdd(&dsumS[dl * 4 + hc], w);
    }
    __syncthreads();

    // normalize + bias + leaky, in place
    for (int i = tid; i < BSIZE * 64; i += 1024) {
        int node = i >> 6, ch = i & 63;
        float dv = dsumS[node * 4 + (ch >> 4)];
        acc[node][ch] = lrelu(acc[node][ch] / dv + b1[ch], 0.01f);
    }
    __syncthreads();

    // fused W2 GEMM: 2 outputs per thread (128 nodes x 16 outch)
    {
        int node = tid >> 3, co = (tid & 7) * 2;
        float g0 = 0.f, g1 = 0.f;
#pragma unroll
        for (int k = 0; k < 64; k++) {
            float av = acc[node][k];
            g0 = fmaf(av, W2s[k * 16 + co], g0);
            g1 = fmaf(av, W2s[k * 16 + co + 1], g1);
        }
        int n = (b << BSH) + node;
        if (n < N_NODES) {
            h2[n * 16 + co] = g0;
            h2[n * 16 + co + 1] = g1;
        }
        atomicAdd(&as2s[node],  g0 * as2w[co] + g1 * as2w[co + 1]);
        atomicAdd(&ad2s2[node], g0 * ad2w[co] + g1 * ad2w[co + 1]);
    }
    __syncthreads();
    if (tid < BSIZE) {
        int n = (b << BSH) + tid;
        if (n < N_NODES) { as2[n] = as2s[tid]; ad2[n] = ad2s2[tid]; }
    }
}

// ---- Fused layer-2 aggregation + final linear: per-bucket LDS accumulators ----
__global__ __launch_bounds__(1024) void k_fused2(
    const int* __restrict__ bcur, const uint32_t* __restrict__ binned,
    const float* __restrict__ as2, const float* __restrict__ ad2,
    const float* __restrict__ h2,
    const float* __restrict__ b2, const float* __restrict__ Wo,
    const float* __restrict__ bo, float* __restrict__ out) {
    __shared__ float acc2[BSIZE][17];
    __shared__ float dsum2[BSIZE];
    __shared__ float ad2s[BSIZE];
    int b = blockIdx.x, tid = threadIdx.x;
    int p0 = b << CSH;
    int L = bcur[b];

    for (int i = tid; i < BSIZE * 17; i += 1024) ((float*)acc2)[i] = 0.f;
    if (tid < BSIZE) {
        dsum2[tid] = 0.f;
        int n = (b << BSH) + tid;
        ad2s[tid] = (n < N_NODES) ? ad2[n] : 0.f;
    }
    __syncthreads();

    int lane = tid & 63, wv = tid >> 6;
    int q = lane >> 4, cl = lane & 15;
    int off = wv * 4 + q;

    for (int e0 = 0; e0 < L; e0 += 64) {
        int idx = e0 + off;
        bool pred = idx < L;
        uint32_t ewd = binned[p0 + (pred ? idx : L - 1)];
        int s = (int)(ewd & 0xFFFF);
        int dl = (int)(ewd >> 16);
        float e = as2[s] + ad2s[dl];
        float w = __expf(e >= 0.f ? e : 0.2f * e);
        w = pred ? w : 0.f;
        float hv = h2[s * 16 + cl];
        atomicAdd(&acc2[dl][cl], w * hv);
        if (cl == 0) atomicAdd(&dsum2[dl], w);
    }
    __syncthreads();

    // y = lrelu(acc/dsum + b2) * Wo, in place
    for (int i = tid; i < BSIZE * 16; i += 1024) {
        int node = i >> 4, c = i & 15;
        float y = lrelu(acc2[node][c] / dsum2[node] + b2[c], 0.01f) * Wo[c];
        acc2[node][c] = y;
    }
    __syncthreads();
    if (tid < BSIZE) {
        int n = (b << BSH) + tid;
        if (n < N_NODES) {
            float sum = bo[0];
#pragma unroll
            for (int c = 0; c < 16; c++) sum += acc2[tid][c];
            out[n] = sum;
        }
    }
}

extern "C" void kernel_launch(void* const* d_in, const int* in_sizes, int n_in,
                              void* d_out, int out_size, void* d_ws, size_t ws_size,
                              hipStream_t stream) {
    const float* x    = (const float*)d_in[0];
    const int*   ei   = (const int*)d_in[1];
    const float* W1   = (const float*)d_in[2];
    const float* as1w = (const float*)d_in[3];
    const float* ad1w = (const float*)d_in[4];
    const float* b1   = (const float*)d_in[5];
    const float* W2   = (const float*)d_in[6];
    const float* as2w = (const float*)d_in[7];
    const float* ad2w = (const float*)d_in[8];
    const float* b2   = (const float*)d_in[9];
    const float* Wo   = (const float*)d_in[10];
    const float* bo   = (const float*)d_in[11];
    float* out = (float*)d_out;

    const int* srcp = ei;
    const int* dstp = ei + N_EDGES;

    char* p = (char*)d_ws;
    auto alloc = [&](size_t bytes) -> char* {
        char* r = p;
        p += (bytes + 255) / 256 * 256;
        return r;
    };
    int*      bcur   = (int*)alloc((size_t)(NBUCKET + 1) * 4);
    uint32_t* binned = (uint32_t*)alloc((size_t)NBUCKET * CAP * 4);
    uint32_t* h1b    = (uint32_t*)alloc((size_t)N_NODES * 32 * 4);
    float*    as1    = (float*)alloc((size_t)N_NODES * 4 * 4);
    float*    ad1    = (float*)alloc((size_t)N_NODES * 4 * 4);
    float*    h2     = (float*)alloc((size_t)N_NODES * 16 * 4);
    float*    as2    = (float*)alloc((size_t)N_NODES * 4);
    float*    ad2    = (float*)alloc((size_t)N_NODES * 4);

    hipMemsetAsync(bcur, 0, (size_t)(NBUCKET + 1) * 4, stream);

    k_gemm1<<<N_NODES / 16, 256, 0, stream>>>(x, W1, as1w, ad1w, h1b, as1, ad1);
    kA_bin<<<256, 256, 0, stream>>>(srcp, dstp, bcur, binned);
    k_fused1<<<NBUCKET, 1024, 0, stream>>>(bcur, binned, as1, ad1, h1b, b1, W2, as2w, ad2w, h2, as2, ad2);
    k_fused2<<<NBUCKET, 1024, 0, stream>>>(bcur, binned, as2, ad2, h2, b2, Wo, bo, out);
}

// Round 10
// 230.119 us; speedup vs baseline: 4.7089x; 4.7089x over previous
//
#include <hip/hip_runtime.h>
#include <hip/hip_bf16.h>
#include <cstdint>

#define N_NODES 50000
#define N_EDGES 1600000
#define EE (N_EDGES + N_NODES)
#define BSH 7
#define BSIZE 128
#define NBUCKET ((N_NODES + BSIZE - 1) >> BSH)   // 391
#define CSH 13
#define CAP 8192                                  // pow2 bucket capacity (mean fill 4224)
#define GEMM_BLOCKS 3125                          // 3125*16 == 50000
#define BIN_BLOCKS 256

__device__ __forceinline__ float lrelu(float x, float s) { return x >= 0.f ? x : s * x; }
__device__ __forceinline__ float bflo(uint32_t v) { return __uint_as_float(v << 16); }
__device__ __forceinline__ float bfhi(uint32_t v) { return __uint_as_float(v & 0xFFFF0000u); }
__device__ __forceinline__ uint32_t bfpackhi(float a) {
    uint32_t u = __float_as_uint(a);
    u += 0x7FFF + ((u >> 16) & 1);
    return u & 0xFFFF0000u;
}
__device__ __forceinline__ uint32_t packbf(float a, float b) {
    uint32_t ua = __float_as_uint(a), ub = __float_as_uint(b);
    ua += 0x7FFF + ((ua >> 16) & 1);
    ub += 0x7FFF + ((ub >> 16) & 1);
    return (ua >> 16) | (ub & 0xFFFF0000u);
}
__device__ __forceinline__ float rdlane(float v, int l) {
    return __uint_as_float(__builtin_amdgcn_readlane(__float_as_uint(v), l));
}

// ---------------- Fused: layer-1 GEMM (blocks 0..3124) + edge binning (blocks 3125..3380) ----------------
__global__ __launch_bounds__(256) void k_pre(
    const float* __restrict__ x, const float* __restrict__ W1,
    const float* __restrict__ as_w, const float* __restrict__ ad_w,
    uint32_t* __restrict__ h1b, float* __restrict__ as1, float* __restrict__ ad1,
    const int* __restrict__ src, const int* __restrict__ dst,
    int* __restrict__ bcur, uint32_t* __restrict__ binned) {
    if (blockIdx.x < GEMM_BLOCKS) {
        int c = threadIdx.x & 63;
        int wv = threadIdx.x >> 6;
        float wreg[64];
#pragma unroll
        for (int k = 0; k < 64; k++) wreg[k] = W1[k * 64 + c];
        float aw = as_w[c];
        float dw = ad_w[c];
        int base = blockIdx.x * 16 + wv * 4;
#pragma unroll
        for (int r = 0; r < 4; r++) {
            int n = base + r;
            float xr = x[n * 64 + c];
            float a0 = 0.f, a1 = 0.f, a2 = 0.f, a3 = 0.f;
#pragma unroll
            for (int k = 0; k < 64; k += 4) {
                a0 = fmaf(rdlane(xr, k),     wreg[k],     a0);
                a1 = fmaf(rdlane(xr, k + 1), wreg[k + 1], a1);
                a2 = fmaf(rdlane(xr, k + 2), wreg[k + 2], a2);
                a3 = fmaf(rdlane(xr, k + 3), wreg[k + 3], a3);
            }
            float acc = (a0 + a1) + (a2 + a3);
            float other = __shfl_xor(acc, 1, 64);
            if (!(c & 1)) h1b[n * 32 + (c >> 1)] = packbf(acc, other);
            float asv = acc * aw;
            float adv = acc * dw;
#pragma unroll
            for (int off = 1; off < 16; off <<= 1) {
                asv += __shfl_xor(asv, off, 64);
                adv += __shfl_xor(adv, off, 64);
            }
            if ((c & 15) == 0) { as1[n * 4 + (c >> 4)] = asv; ad1[n * 4 + (c >> 4)] = adv; }
        }
        return;
    }
    // ---- binning half ----
    __shared__ int lcnt[NBUCKET];
    __shared__ int lbase[NBUCKET];
    int bid = blockIdx.x - GEMM_BLOCKS;
    const int T = 16;
    const int CHUNK = 256 * T;
    int nchunks = (EE + CHUNK - 1) / CHUNK;
    for (int ch = bid; ch < nchunks; ch += BIN_BLOCKS) {
        for (int i = threadIdx.x; i < NBUCKET; i += 256) lcnt[i] = 0;
        __syncthreads();
        uint32_t pv[T];
        uint32_t pm[T];
        int base = ch * CHUNK;
#pragma unroll
        for (int k = 0; k < T; k++) {
            int e = base + k * 256 + threadIdx.x;
            if (e < EE) {
                int s, d;
                if (e < N_EDGES) { s = src[e]; d = dst[e]; } else { s = e - N_EDGES; d = s; }
                int b = d >> BSH;
                int r = atomicAdd(&lcnt[b], 1);
                pv[k] = (uint32_t)s | ((uint32_t)(d & (BSIZE - 1)) << 16);
                pm[k] = (uint32_t)r | ((uint32_t)b << 16);
            }
        }
        __syncthreads();
        for (int i = threadIdx.x; i < NBUCKET; i += 256) {
            int c = lcnt[i];
            if (c) lbase[i] = atomicAdd(&bcur[i], c);
        }
        __syncthreads();
#pragma unroll
        for (int k = 0; k < T; k++) {
            int e = base + k * 256 + threadIdx.x;
            if (e < EE) {
                int b = pm[k] >> 16, r = pm[k] & 0xFFFF;
                binned[((size_t)b << CSH) + lbase[b] + r] = pv[k];
            }
        }
        __syncthreads();
    }
}

// ---------------- Phase B: counting sort -> CSR + packed layer-1 weights ----------------
// rowdesc[node] = off(13b) | deg(<<13);  sbn[pos] = s | dlocal<<16;  wbuf[pos] = {bf16x2(w0,w1), bf16x2(w2,w3)}
__global__ __launch_bounds__(512) void kB_sort(const int* __restrict__ bcur, const uint32_t* __restrict__ binned,
                                               const float* __restrict__ as1, const float* __restrict__ ad1,
                                               int* __restrict__ rowdesc, uint32_t* __restrict__ sbn,
                                               uint32_t* __restrict__ wbuf) {
    int b = blockIdx.x, tid = threadIdx.x;
    int p0 = b << CSH;
    int L = bcur[b];
    __shared__ int ncnt[BSIZE];
    __shared__ int sh[BSIZE];
    __shared__ int ncur[BSIZE];
    if (tid < BSIZE) ncnt[tid] = 0;
    __syncthreads();
    for (int i = tid; i < L; i += 512) {
        uint32_t v = binned[p0 + i];
        atomicAdd(&ncnt[(v >> 16) & (BSIZE - 1)], 1);
    }
    __syncthreads();
    int v0 = 0;
    if (tid < BSIZE) { v0 = ncnt[tid]; sh[tid] = v0; }
    __syncthreads();
    for (int off = 1; off < BSIZE; off <<= 1) {
        int t = 0;
        if (tid < BSIZE && tid >= off) t = sh[tid - off];
        __syncthreads();
        if (tid < BSIZE && tid >= off) sh[tid] += t;
        __syncthreads();
    }
    if (tid < BSIZE) {
        int excl = sh[tid] - v0;
        int node = (b << BSH) + tid;
        if (node < N_NODES) rowdesc[node] = excl | (v0 << 13);
        ncur[tid] = excl;
    }
    __syncthreads();
    for (int i = tid; i < L; i += 512) {
        uint32_t v = binned[p0 + i];
        int dl = (v >> 16) & (BSIZE - 1);
        int s = (int)(v & 0xFFFF);
        int pos = atomicAdd(&ncur[dl], 1);
        int node = (b << BSH) + dl;
        float4 a = *(const float4*)(as1 + s * 4);
        float4 d = *(const float4*)(ad1 + node * 4);
        float e0 = a.x + d.x, e1 = a.y + d.y, e2 = a.z + d.z, e3 = a.w + d.w;
        float w0 = __expf(e0 >= 0.f ? e0 : 0.2f * e0);
        float w1 = __expf(e1 >= 0.f ? e1 : 0.2f * e1);
        float w2 = __expf(e2 >= 0.f ? e2 : 0.2f * e2);
        float w3 = __expf(e3 >= 0.f ? e3 : 0.2f * e3);
        sbn[p0 + pos] = (uint32_t)s | ((uint32_t)dl << 16);
        wbuf[(size_t)(p0 + pos) * 2]     = packbf(w0, w1);
        wbuf[(size_t)(p0 + pos) * 2 + 1] = packbf(w2, w3);
    }
}

// ---------------- Layer 1 aggregation + fused L2 GEMM: flat loop, 4 nodes/block ----------------
__global__ __launch_bounds__(256) void k_aggr1f(
    const int* __restrict__ rowdesc, const uint32_t* __restrict__ sbn,
    const uint32_t* __restrict__ wbuf, const uint32_t* __restrict__ h1b,
    const float* __restrict__ b1, const float* __restrict__ W2,
    const float* __restrict__ as2w, const float* __restrict__ ad2w,
    float* __restrict__ h2, float* __restrict__ as2, float* __restrict__ ad2) {
    int n = blockIdx.x * 4 + (threadIdx.x >> 6);
    int lane = threadIdx.x & 63;
    int md = rowdesc[n];
    int begin = ((n >> BSH) << CSH) + (md & (CAP - 1));
    int deg = md >> 13;

    int q = lane >> 4, cl = lane & 15;    // quarter q = edge slot; lane covers ch 4cl..4cl+3
    int hc = cl >> 2;
    int wsel = hc >> 1, whalf = hc & 1;

    const uint2* h1b2 = (const uint2*)h1b;
    float acc0 = 0.f, acc1 = 0.f, acc2 = 0.f, acc3 = 0.f, dsum = 0.f;

    int iters = (deg + 3) >> 2;
#pragma unroll 4
    for (int it = 0; it < iters; it++) {
        int idx = it * 4 + q;
        uint32_t sv = sbn[begin + idx];                          // broadcast across 16 lanes
        uint32_t wp = wbuf[(size_t)(begin + idx) * 2 + wsel];
        float w = whalf ? bfhi(wp) : bflo(wp);
        w = (idx < deg) ? w : 0.f;
        int s = (int)(sv & 0xFFFF);
        uint2 v = h1b2[s * 16 + cl];
        dsum += w;
        acc0 += w * bflo(v.x);
        acc1 += w * bfhi(v.x);
        acc2 += w * bflo(v.y);
        acc3 += w * bfhi(v.y);
    }
#pragma unroll
    for (int off = 16; off <= 32; off <<= 1) {
        acc0 += __shfl_xor(acc0, off, 64);
        acc1 += __shfl_xor(acc1, off, 64);
        acc2 += __shfl_xor(acc2, off, 64);
        acc3 += __shfl_xor(acc3, off, 64);
        dsum += __shfl_xor(dsum, off, 64);
    }
    float dinv = 1.f / dsum;

    float4 bb = *(const float4*)(b1 + 4 * cl);
    float act0 = lrelu(acc0 * dinv + bb.x, 0.01f);
    float act1 = lrelu(acc1 * dinv + bb.y, 0.01f);
    float act2 = lrelu(acc2 * dinv + bb.z, 0.01f);
    float act3 = lrelu(acc3 * dinv + bb.w, 0.01f);

    // fused L2 GEMM via shfl: lane (q,cl) sums k = 16q..16q+15 for output channel cl
    float g = 0.f;
#pragma unroll
    for (int jj = 0; jj < 4; jj++) {
        int srcl = 4 * q + jj;
        float a0 = __shfl(act0, srcl, 64);
        float a1 = __shfl(act1, srcl, 64);
        float a2 = __shfl(act2, srcl, 64);
        float a3 = __shfl(act3, srcl, 64);
        const float* w2r = W2 + (16 * q + 4 * jj) * 16 + cl;
        g = fmaf(a0, w2r[0],  g);
        g = fmaf(a1, w2r[16], g);
        g = fmaf(a2, w2r[32], g);
        g = fmaf(a3, w2r[48], g);
    }
    g += __shfl_xor(g, 16, 64);
    g += __shfl_xor(g, 32, 64);
    if (lane < 16) h2[n * 16 + cl] = g;
    float asv = g * as2w[cl];
    float adv2 = g * ad2w[cl];
#pragma unroll
    for (int off = 1; off < 16; off <<= 1) {
        asv += __shfl_xor(asv, off, 64);
        adv2 += __shfl_xor(adv2, off, 64);
    }
    if (lane == 0) { as2[n] = asv; ad2[n] = adv2; }
}

// ---------------- Layer-2 edge weights (reads sorted sbn; one exp per edge) ----------------
__global__ __launch_bounds__(256) void k_w2(
    const int* __restrict__ bcur, const uint32_t* __restrict__ sbn,
    const float* __restrict__ as2, const float* __restrict__ ad2,
    uint32_t* __restrict__ earr2) {
    int slot = blockIdx.x * 256 + threadIdx.x;
    int b = slot >> CSH, i = slot & (CAP - 1);
    if (i >= bcur[b]) return;
    uint32_t v = sbn[slot];
    int s = (int)(v & 0xFFFF);
    int node = (b << BSH) + (int)(v >> 16);
    float e = as2[s] + ad2[node];
    float w = __expf(e >= 0.f ? e : 0.2f * e);
    earr2[slot] = bfpackhi(w) | (uint32_t)s;
}

// ---------------- Layer 2 aggregation + final linear: flat loop ----------------
__global__ __launch_bounds__(256) void k_aggr2(
    const int* __restrict__ rowdesc, const uint32_t* __restrict__ earr2,
    const float* __restrict__ h2,
    const float* __restrict__ b2, const float* __restrict__ Wo,
    const float* __restrict__ bo, float* __restrict__ out) {
    int n = blockIdx.x * 4 + (threadIdx.x >> 6);
    int lane = threadIdx.x & 63;
    int md = rowdesc[n];
    int begin = ((n >> BSH) << CSH) + (md & (CAP - 1));
    int deg = md >> 13;

    int q = lane >> 4, cl = lane & 15;
    const uint32_t* ep = earr2 + begin + q;
    float acc = 0.f, dsum = 0.f;

    int iters = (deg + 3) >> 2;
#pragma unroll 4
    for (int it = 0; it < iters; it++) {
        int idx = it * 4 + q;
        uint32_t ewd = ep[it * 4];
        float w = __uint_as_float(ewd & 0xFFFF0000u);
        w = (idx < deg) ? w : 0.f;
        int s = (int)(ewd & 0xFFFF);
        acc += w * h2[s * 16 + cl];
        dsum += w;
    }
    acc += __shfl_xor(acc, 16, 64);
    acc += __shfl_xor(acc, 32, 64);
    dsum += __shfl_xor(dsum, 16, 64);
    dsum += __shfl_xor(dsum, 32, 64);

    float val = acc / dsum + b2[cl];
    float y = lrelu(val, 0.01f) * Wo[cl];
#pragma unroll
    for (int off = 1; off < 16; off <<= 1) y += __shfl_xor(y, off, 64);
    if (lane == 0) out[n] = y + bo[0];
}

extern "C" void kernel_launch(void* const* d_in, const int* in_sizes, int n_in,
                              void* d_out, int out_size, void* d_ws, size_t ws_size,
                              hipStream_t stream) {
    const float* x    = (const float*)d_in[0];
    const int*   ei   = (const int*)d_in[1];
    const float* W1   = (const float*)d_in[2];
    const float* as1w = (const float*)d_in[3];
    const float* ad1w = (const float*)d_in[4];
    const float* b1   = (const float*)d_in[5];
    const float* W2   = (const float*)d_in[6];
    const float* as2w = (const float*)d_in[7];
    const float* ad2w = (const float*)d_in[8];
    const float* b2   = (const float*)d_in[9];
    const float* Wo   = (const float*)d_in[10];
    const float* bo   = (const float*)d_in[11];
    float* out = (float*)d_out;

    const int* srcp = ei;
    const int* dstp = ei + N_EDGES;

    char* p = (char*)d_ws;
    auto alloc = [&](size_t bytes) -> char* {
        char* r = p;
        p += (bytes + 255) / 256 * 256;
        return r;
    };
    // layout: tail-garbage gathers (masked s <= 65535) must land in allocated space:
    // h2 needs ~4.2MB after its start (h1b follows); h1b needs ~8.4MB after its start
    // (as1/ad1/as2/ad2/pad follow).
    int*      bcur    = (int*)alloc((size_t)(NBUCKET + 1) * 4);
    int*      rowdesc = (int*)alloc((size_t)N_NODES * 4);
    uint32_t* binned  = (uint32_t*)alloc((size_t)NBUCKET * CAP * 4);
    uint32_t* sbn     = (uint32_t*)alloc((size_t)NBUCKET * CAP * 4 + 256);
    uint32_t* wbuf    = (uint32_t*)alloc((size_t)NBUCKET * CAP * 8 + 256);
    uint32_t* earr2   = (uint32_t*)alloc((size_t)NBUCKET * CAP * 4 + 256);
    float*    h2      = (float*)alloc((size_t)N_NODES * 16 * 4);
    uint32_t* h1b     = (uint32_t*)alloc((size_t)N_NODES * 32 * 4);
    float*    as1     = (float*)alloc((size_t)N_NODES * 4 * 4);
    float*    ad1     = (float*)alloc((size_t)N_NODES * 4 * 4);
    float*    as2     = (float*)alloc((size_t)N_NODES * 4);
    float*    ad2     = (float*)alloc((size_t)N_NODES * 4);
    (void)alloc(2 * 1024 * 1024);   // safety pad for masked tail gathers

    hipMemsetAsync(bcur, 0, (size_t)(NBUCKET + 1) * 4, stream);

    k_pre<<<GEMM_BLOCKS + BIN_BLOCKS, 256, 0, stream>>>(x, W1, as1w, ad1w, h1b, as1, ad1,
                                                        srcp, dstp, bcur, binned);
    kB_sort<<<NBUCKET, 512, 0, stream>>>(bcur, binned, as1, ad1, rowdesc, sbn, wbuf);
    k_aggr1f<<<N_NODES / 4, 256, 0, stream>>>(rowdesc, sbn, wbuf, h1b, b1, W2, as2w, ad2w, h2, as2, ad2);
    k_w2<<<NBUCKET * (CAP / 256), 256, 0, stream>>>(bcur, sbn, as2, ad2, earr2);
    k_aggr2<<<N_NODES / 4, 256, 0, stream>>>(rowdesc, earr2, h2, b2, Wo, bo, out);
}

// Round 11
// 218.855 us; speedup vs baseline: 4.9512x; 1.0515x over previous
//
#include <hip/hip_runtime.h>
#include <hip/hip_bf16.h>
#include <cstdint>

#define N_NODES 50000
#define N_EDGES 1600000
#define EE (N_EDGES + N_NODES)
#define BSH 7
#define BSIZE 128
#define NBUCKET ((N_NODES + BSIZE - 1) >> BSH)   // 391
#define CSH 13
#define CAP 8192                                  // pow2 bucket capacity (mean fill 4224)
#define BIN_BLOCKS 403                            // ceil(EE/4096) -- one chunk per block
#define GEMM_BLOCKS 3125                          // 3125*16 == 50000

__device__ __forceinline__ float lrelu(float x, float s) { return x >= 0.f ? x : s * x; }
__device__ __forceinline__ float bflo(uint32_t v) { return __uint_as_float(v << 16); }
__device__ __forceinline__ float bfhi(uint32_t v) { return __uint_as_float(v & 0xFFFF0000u); }
__device__ __forceinline__ uint32_t bfpackhi(float a) {
    uint32_t u = __float_as_uint(a);
    u += 0x7FFF + ((u >> 16) & 1);
    return u & 0xFFFF0000u;
}
__device__ __forceinline__ uint32_t packbf(float a, float b) {
    uint32_t ua = __float_as_uint(a), ub = __float_as_uint(b);
    ua += 0x7FFF + ((ua >> 16) & 1);
    ub += 0x7FFF + ((ub >> 16) & 1);
    return (ua >> 16) | (ub & 0xFFFF0000u);
}
__device__ __forceinline__ float rdlane(float v, int l) {
    return __uint_as_float(__builtin_amdgcn_readlane(__float_as_uint(v), l));
}

// -------- Fused: edge binning (blocks 0..402, dispatched first) + layer-1 GEMM (rest) --------
__global__ __launch_bounds__(256) void k_pre(
    const float* __restrict__ x, const float* __restrict__ W1,
    const float* __restrict__ as_w, const float* __restrict__ ad_w,
    uint32_t* __restrict__ h1b, float* __restrict__ as1, float* __restrict__ ad1,
    const int* __restrict__ src, const int* __restrict__ dst,
    int* __restrict__ bcur, uint32_t* __restrict__ binned) {
    if (blockIdx.x < BIN_BLOCKS) {
        __shared__ int lcnt[NBUCKET];
        __shared__ int lbase[NBUCKET];
        const int T = 16;
        for (int i = threadIdx.x; i < NBUCKET; i += 256) lcnt[i] = 0;
        __syncthreads();
        uint32_t pv[T];
        uint32_t pm[T];
        int base = blockIdx.x * (256 * T);
#pragma unroll
        for (int k = 0; k < T; k++) {
            int e = base + k * 256 + threadIdx.x;
            if (e < EE) {
                int s, d;
                if (e < N_EDGES) { s = src[e]; d = dst[e]; } else { s = e - N_EDGES; d = s; }
                int b = d >> BSH;
                int r = atomicAdd(&lcnt[b], 1);
                pv[k] = (uint32_t)s | ((uint32_t)(d & (BSIZE - 1)) << 16);
                pm[k] = (uint32_t)r | ((uint32_t)b << 16);
            }
        }
        __syncthreads();
        for (int i = threadIdx.x; i < NBUCKET; i += 256) {
            int c = lcnt[i];
            if (c) lbase[i] = atomicAdd(&bcur[i], c);
        }
        __syncthreads();
#pragma unroll
        for (int k = 0; k < T; k++) {
            int e = base + k * 256 + threadIdx.x;
            if (e < EE) {
                int b = pm[k] >> 16, r = pm[k] & 0xFFFF;
                binned[((size_t)b << CSH) + lbase[b] + r] = pv[k];
            }
        }
        return;
    }
    // ---- layer-1 GEMM half ----
    int c = threadIdx.x & 63;
    int wv = threadIdx.x >> 6;
    float wreg[64];
#pragma unroll
    for (int k = 0; k < 64; k++) wreg[k] = W1[k * 64 + c];
    float aw = as_w[c];
    float dw = ad_w[c];
    int base = (blockIdx.x - BIN_BLOCKS) * 16 + wv * 4;
#pragma unroll
    for (int r = 0; r < 4; r++) {
        int n = base + r;
        float xr = x[n * 64 + c];
        float a0 = 0.f, a1 = 0.f, a2 = 0.f, a3 = 0.f;
#pragma unroll
        for (int k = 0; k < 64; k += 4) {
            a0 = fmaf(rdlane(xr, k),     wreg[k],     a0);
            a1 = fmaf(rdlane(xr, k + 1), wreg[k + 1], a1);
            a2 = fmaf(rdlane(xr, k + 2), wreg[k + 2], a2);
            a3 = fmaf(rdlane(xr, k + 3), wreg[k + 3], a3);
        }
        float acc = (a0 + a1) + (a2 + a3);
        float other = __shfl_xor(acc, 1, 64);
        if (!(c & 1)) h1b[n * 32 + (c >> 1)] = packbf(acc, other);
        float asv = acc * aw;
        float adv = acc * dw;
#pragma unroll
        for (int off = 1; off < 16; off <<= 1) {
            asv += __shfl_xor(asv, off, 64);
            adv += __shfl_xor(adv, off, 64);
        }
        if ((c & 15) == 0) { as1[n * 4 + (c >> 4)] = asv; ad1[n * 4 + (c >> 4)] = adv; }
    }
}

// -------- Phase B: rank-capture counting sort (no cursor atomics, single binned pass) --------
// rowdesc[node] = off(13b) | deg(<<13);  sbn[pos] = s | dlocal<<16;  wbuf[pos] = bf16x2{w0,w1},{w2,w3}
__global__ __launch_bounds__(512) void kB_sort(const int* __restrict__ bcur, const uint32_t* __restrict__ binned,
                                               const float* __restrict__ as1, const float* __restrict__ ad1,
                                               int* __restrict__ rowdesc, uint32_t* __restrict__ sbn,
                                               uint32_t* __restrict__ wbuf) {
    int b = blockIdx.x, tid = threadIdx.x, wv = tid >> 6;
    int p0 = b << CSH;
    int L = bcur[b];
    __shared__ int cnt8[8][BSIZE];     // per-wave histograms
    __shared__ int wbase[8][BSIZE];
    __shared__ int shs[BSIZE];
    for (int i = tid; i < 8 * BSIZE; i += 512) ((int*)cnt8)[i] = 0;
    __syncthreads();

    uint32_t pv[16];
    unsigned short rk[16];
#pragma unroll
    for (int k = 0; k < 16; k++) {
        int i = tid + k * 512;
        if (i < L) {
            uint32_t v = binned[p0 + i];
            pv[k] = v;
            rk[k] = (unsigned short)atomicAdd(&cnt8[wv][(v >> 16) & (BSIZE - 1)], 1);
        }
    }
    __syncthreads();

    int tot = 0;
    if (tid < BSIZE) {
#pragma unroll
        for (int w = 0; w < 8; w++) tot += cnt8[w][tid];
        shs[tid] = tot;
    }
    __syncthreads();
    for (int off = 1; off < BSIZE; off <<= 1) {
        int t = 0;
        if (tid < BSIZE && tid >= off) t = shs[tid - off];
        __syncthreads();
        if (tid < BSIZE && tid >= off) shs[tid] += t;
        __syncthreads();
    }
    if (tid < BSIZE) {
        int excl = shs[tid] - tot;
        int node = (b << BSH) + tid;
        if (node < N_NODES) rowdesc[node] = excl | (tot << 13);
        int wb = excl;
#pragma unroll
        for (int w = 0; w < 8; w++) { wbase[w][tid] = wb; wb += cnt8[w][tid]; }
    }
    __syncthreads();

#pragma unroll
    for (int k = 0; k < 16; k++) {
        int i = tid + k * 512;
        if (i < L) {
            uint32_t v = pv[k];
            int dl = (v >> 16) & (BSIZE - 1);
            int s = (int)(v & 0xFFFF);
            int pos = wbase[wv][dl] + (int)rk[k];
            int node = (b << BSH) + dl;
            float4 a = *(const float4*)(as1 + s * 4);
            float4 d = *(const float4*)(ad1 + node * 4);
            float e0 = a.x + d.x, e1 = a.y + d.y, e2 = a.z + d.z, e3 = a.w + d.w;
            float w0 = __expf(e0 >= 0.f ? e0 : 0.2f * e0);
            float w1 = __expf(e1 >= 0.f ? e1 : 0.2f * e1);
            float w2 = __expf(e2 >= 0.f ? e2 : 0.2f * e2);
            float w3 = __expf(e3 >= 0.f ? e3 : 0.2f * e3);
            sbn[p0 + pos] = (uint32_t)s | ((uint32_t)dl << 16);
            wbuf[(size_t)(p0 + pos) * 2]     = packbf(w0, w1);
            wbuf[(size_t)(p0 + pos) * 2 + 1] = packbf(w2, w3);
        }
    }
}

// -------- Layer 1 aggregation + fused L2 GEMM: 8 edges/iter, uint4 loads, 4 nodes/block --------
__global__ __launch_bounds__(256) void k_aggr1f(
    const int* __restrict__ rowdesc, const uint32_t* __restrict__ sbn,
    const uint32_t* __restrict__ wbuf, const uint32_t* __restrict__ h1b,
    const float* __restrict__ b1, const float* __restrict__ W2,
    const float* __restrict__ as2w, const float* __restrict__ ad2w,
    float* __restrict__ h2, float* __restrict__ as2, float* __restrict__ ad2) {
    int n = blockIdx.x * 4 + (threadIdx.x >> 6);
    int lane = threadIdx.x & 63;
    int md = rowdesc[n];
    int begin = ((n >> BSH) << CSH) + (md & (CAP - 1));
    int deg = md >> 13;

    int slot = lane >> 3, cl = lane & 7;   // lane covers channels 8cl..8cl+7, edge slot = slot
    int hc = cl >> 1;                      // head
    int wsel = hc >> 1, whalf = hc & 1;

    const uint4* h1b4 = (const uint4*)h1b;
    float a0 = 0.f, a1 = 0.f, a2 = 0.f, a3 = 0.f, a4 = 0.f, a5 = 0.f, a6 = 0.f, a7 = 0.f, dsum = 0.f;

    int iters = (deg + 7) >> 3;
#pragma unroll 4
    for (int it = 0; it < iters; it++) {
        int idx = it * 8 + slot;
        uint32_t sv = sbn[begin + idx];
        uint32_t wp = wbuf[(size_t)(begin + idx) * 2 + wsel];
        float w = whalf ? bfhi(wp) : bflo(wp);
        w = (idx < deg) ? w : 0.f;
        int s = (int)(sv & 0xFFFF);
        uint4 v = h1b4[s * 8 + cl];
        dsum += w;
        a0 += w * bflo(v.x); a1 += w * bfhi(v.x);
        a2 += w * bflo(v.y); a3 += w * bfhi(v.y);
        a4 += w * bflo(v.z); a5 += w * bfhi(v.z);
        a6 += w * bflo(v.w); a7 += w * bfhi(v.w);
    }
#pragma unroll
    for (int off = 8; off <= 32; off <<= 1) {
        a0 += __shfl_xor(a0, off, 64); a1 += __shfl_xor(a1, off, 64);
        a2 += __shfl_xor(a2, off, 64); a3 += __shfl_xor(a3, off, 64);
        a4 += __shfl_xor(a4, off, 64); a5 += __shfl_xor(a5, off, 64);
        a6 += __shfl_xor(a6, off, 64); a7 += __shfl_xor(a7, off, 64);
        dsum += __shfl_xor(dsum, off, 64);
    }
    float dinv = 1.f / dsum;               // full denom of head hc

    float4 bb0 = *(const float4*)(b1 + 8 * cl);
    float4 bb1 = *(const float4*)(b1 + 8 * cl + 4);
    float act0 = lrelu(a0 * dinv + bb0.x, 0.01f);
    float act1 = lrelu(a1 * dinv + bb0.y, 0.01f);
    float act2 = lrelu(a2 * dinv + bb0.z, 0.01f);
    float act3 = lrelu(a3 * dinv + bb0.w, 0.01f);
    float act4 = lrelu(a4 * dinv + bb1.x, 0.01f);
    float act5 = lrelu(a5 * dinv + bb1.y, 0.01f);
    float act6 = lrelu(a6 * dinv + bb1.z, 0.01f);
    float act7 = lrelu(a7 * dinv + bb1.w, 0.01f);

    // fused L2 GEMM: lane (kg, co) sums k = 16kg..16kg+15 for output channel co
    int co = lane & 15, kg = lane >> 4;
    int l0 = 2 * kg, l1 = 2 * kg + 1;      // source lanes holding ch 16kg.. and 16kg+8..
    const float* w2r = W2 + (16 * kg) * 16 + co;
    float g = 0.f;
    g = fmaf(__shfl(act0, l0, 64), w2r[0 * 16],  g);
    g = fmaf(__shfl(act1, l0, 64), w2r[1 * 16],  g);
    g = fmaf(__shfl(act2, l0, 64), w2r[2 * 16],  g);
    g = fmaf(__shfl(act3, l0, 64), w2r[3 * 16],  g);
    g = fmaf(__shfl(act4, l0, 64), w2r[4 * 16],  g);
    g = fmaf(__shfl(act5, l0, 64), w2r[5 * 16],  g);
    g = fmaf(__shfl(act6, l0, 64), w2r[6 * 16],  g);
    g = fmaf(__shfl(act7, l0, 64), w2r[7 * 16],  g);
    g = fmaf(__shfl(act0, l1, 64), w2r[8 * 16],  g);
    g = fmaf(__shfl(act1, l1, 64), w2r[9 * 16],  g);
    g = fmaf(__shfl(act2, l1, 64), w2r[10 * 16], g);
    g = fmaf(__shfl(act3, l1, 64), w2r[11 * 16], g);
    g = fmaf(__shfl(act4, l1, 64), w2r[12 * 16], g);
    g = fmaf(__shfl(act5, l1, 64), w2r[13 * 16], g);
    g = fmaf(__shfl(act6, l1, 64), w2r[14 * 16], g);
    g = fmaf(__shfl(act7, l1, 64), w2r[15 * 16], g);
    g += __shfl_xor(g, 16, 64);
    g += __shfl_xor(g, 32, 64);
    if (lane < 16) h2[n * 16 + co] = g;
    float asv = g * as2w[co];
    float adv2 = g * ad2w[co];
#pragma unroll
    for (int off = 1; off < 16; off <<= 1) {
        asv += __shfl_xor(asv, off, 64);
        adv2 += __shfl_xor(adv2, off, 64);
    }
    if (lane == 0) { as2[n] = asv; ad2[n] = adv2; }
}

// -------- Layer-2 edge weights (reads sorted sbn; one exp per edge) --------
__global__ __launch_bounds__(256) void k_w2(
    const int* __restrict__ bcur, const uint32_t* __restrict__ sbn,
    const float* __restrict__ as2, const float* __restrict__ ad2,
    uint32_t* __restrict__ earr2) {
    int slot = blockIdx.x * 256 + threadIdx.x;
    int b = slot >> CSH, i = slot & (CAP - 1);
    if (i >= bcur[b]) return;
    uint32_t v = sbn[slot];
    int s = (int)(v & 0xFFFF);
    int node = (b << BSH) + (int)(v >> 16);
    float e = as2[s] + ad2[node];
    float w = __expf(e >= 0.f ? e : 0.2f * e);
    earr2[slot] = bfpackhi(w) | (uint32_t)s;
}

// -------- Layer 2 aggregation + final linear: 8 edges/iter, float2 loads --------
__global__ __launch_bounds__(256) void k_aggr2(
    const int* __restrict__ rowdesc, const uint32_t* __restrict__ earr2,
    const float* __restrict__ h2,
    const float* __restrict__ b2, const float* __restrict__ Wo,
    const float* __restrict__ bo, float* __restrict__ out) {
    int n = blockIdx.x * 4 + (threadIdx.x >> 6);
    int lane = threadIdx.x & 63;
    int md = rowdesc[n];
    int begin = ((n >> BSH) << CSH) + (md & (CAP - 1));
    int deg = md >> 13;

    int slot = lane >> 3, c2 = lane & 7;   // lane covers channels 2c2, 2c2+1
    const float2* h22 = (const float2*)h2;
    float acc0 = 0.f, acc1 = 0.f, dsum = 0.f;

    int iters = (deg + 7) >> 3;
#pragma unroll 4
    for (int it = 0; it < iters; it++) {
        int idx = it * 8 + slot;
        uint32_t ewd = earr2[begin + idx];
        float w = __uint_as_float(ewd & 0xFFFF0000u);
        w = (idx < deg) ? w : 0.f;
        int s = (int)(ewd & 0xFFFF);
        float2 hv = h22[s * 8 + c2];
        acc0 += w * hv.x;
        acc1 += w * hv.y;
        dsum += w;
    }
#pragma unroll
    for (int off = 8; off <= 32; off <<= 1) {
        acc0 += __shfl_xor(acc0, off, 64);
        acc1 += __shfl_xor(acc1, off, 64);
        dsum += __shfl_xor(dsum, off, 64);
    }
    float v0 = lrelu(acc0 / dsum + b2[2 * c2], 0.01f) * Wo[2 * c2];
    float v1 = lrelu(acc1 / dsum + b2[2 * c2 + 1], 0.01f) * Wo[2 * c2 + 1];
    float y = v0 + v1;
    y += __shfl_xor(y, 1, 64);
    y += __shfl_xor(y, 2, 64);
    y += __shfl_xor(y, 4, 64);
    if (lane == 0) out[n] = y + bo[0];
}

extern "C" void kernel_launch(void* const* d_in, const int* in_sizes, int n_in,
                              void* d_out, int out_size, void* d_ws, size_t ws_size,
                              hipStream_t stream) {
    const float* x    = (const float*)d_in[0];
    const int*   ei   = (const int*)d_in[1];
    const float* W1   = (const float*)d_in[2];
    const float* as1w = (const float*)d_in[3];
    const float* ad1w = (const float*)d_in[4];
    const float* b1   = (const float*)d_in[5];
    const float* W2   = (const float*)d_in[6];
    const float* as2w = (const float*)d_in[7];
    const float* ad2w = (const float*)d_in[8];
    const float* b2   = (const float*)d_in[9];
    const float* Wo   = (const float*)d_in[10];
    const float* bo   = (const float*)d_in[11];
    float* out = (float*)d_out;

    const int* srcp = ei;
    const int* dstp = ei + N_EDGES;

    char* p = (char*)d_ws;
    auto alloc = [&](size_t bytes) -> char* {
        char* r = p;
        p += (bytes + 255) / 256 * 256;
        return r;
    };
    // layout: masked tail gathers use garbage s <= 65535; keep >=8.4MB allocated after
    // h1b start and >=4.2MB after h2 start.
    int*      bcur    = (int*)alloc((size_t)(NBUCKET + 1) * 4);
    int*      rowdesc = (int*)alloc((size_t)N_NODES * 4);
    uint32_t* binned  = (uint32_t*)alloc((size_t)NBUCKET * CAP * 4);
    uint32_t* sbn     = (uint32_t*)alloc((size_t)NBUCKET * CAP * 4 + 256);
    uint32_t* wbuf    = (uint32_t*)alloc((size_t)NBUCKET * CAP * 8 + 256);
    uint32_t* earr2   = (uint32_t*)alloc((size_t)NBUCKET * CAP * 4 + 256);
    float*    h2      = (float*)alloc((size_t)N_NODES * 16 * 4);
    uint32_t* h1b     = (uint32_t*)alloc((size_t)N_NODES * 32 * 4);
    float*    as1     = (float*)alloc((size_t)N_NODES * 4 * 4);
    float*    ad1     = (float*)alloc((size_t)N_NODES * 4 * 4);
    float*    as2     = (float*)alloc((size_t)N_NODES * 4);
    float*    ad2     = (float*)alloc((size_t)N_NODES * 4);
    (void)alloc(3 * 1024 * 1024);   // safety pad for masked tail gathers

    hipMemsetAsync(bcur, 0, (size_t)(NBUCKET + 1) * 4, stream);

    k_pre<<<BIN_BLOCKS + GEMM_BLOCKS, 256, 0, stream>>>(x, W1, as1w, ad1w, h1b, as1, ad1,
                                                        srcp, dstp, bcur, binned);
    kB_sort<<<NBUCKET, 512, 0, stream>>>(bcur, binned, as1, ad1, rowdesc, sbn, wbuf);
    k_aggr1f<<<N_NODES / 4, 256, 0, stream>>>(rowdesc, sbn, wbuf, h1b, b1, W2, as2w, ad2w, h2, as2, ad2);
    k_w2<<<NBUCKET * (CAP / 256), 256, 0, stream>>>(bcur, sbn, as2, ad2, earr2);
    k_aggr2<<<N_NODES / 4, 256, 0, stream>>>(rowdesc, earr2, h2, b2, Wo, bo, out);
}

// Round 12
// 208.276 us; speedup vs baseline: 5.2027x; 1.0508x over previous
//
#include <hip/hip_runtime.h>
#include <hip/hip_bf16.h>
#include <cstdint>

#define N_NODES 50000
#define N_EDGES 1600000
#define EE (N_EDGES + N_NODES)
#define BSH 7
#define BSIZE 128
#define NBUCKET ((N_NODES + BSIZE - 1) >> BSH)   // 391
#define CSH 13
#define CAP 8192                                  // pow2 bucket capacity (mean fill 4224)
#define BIN_BLOCKS 403                            // ceil(EE/4096) -- one chunk per block
#define GEMM_BLOCKS 3125                          // 3125*16 == 50000

__device__ __forceinline__ float lrelu(float x, float s) { return x >= 0.f ? x : s * x; }
__device__ __forceinline__ float bflo(uint32_t v) { return __uint_as_float(v << 16); }
__device__ __forceinline__ float bfhi(uint32_t v) { return __uint_as_float(v & 0xFFFF0000u); }
__device__ __forceinline__ uint32_t packbf(float a, float b) {
    uint32_t ua = __float_as_uint(a), ub = __float_as_uint(b);
    ua += 0x7FFF + ((ua >> 16) & 1);
    ub += 0x7FFF + ((ub >> 16) & 1);
    return (ua >> 16) | (ub & 0xFFFF0000u);
}

// -------- Fused: edge binning (blocks 0..402, dispatched first) + layer-1 GEMM (rest) --------
__global__ __launch_bounds__(256) void k_pre(
    const float* __restrict__ x, const float* __restrict__ W1,
    const float* __restrict__ as_w, const float* __restrict__ ad_w,
    uint32_t* __restrict__ h1b, float* __restrict__ as1, float* __restrict__ ad1,
    const int* __restrict__ src, const int* __restrict__ dst,
    int* __restrict__ bcur, uint32_t* __restrict__ binned) {
    if (blockIdx.x < BIN_BLOCKS) {
        __shared__ int lcnt[NBUCKET];
        __shared__ int lbase[NBUCKET];
        const int T = 16;
        for (int i = threadIdx.x; i < NBUCKET; i += 256) lcnt[i] = 0;
        __syncthreads();
        uint32_t pv[T];
        uint32_t pm[T];
        int base = blockIdx.x * (256 * T);
#pragma unroll
        for (int k = 0; k < T; k++) {
            int e = base + k * 256 + threadIdx.x;
            if (e < EE) {
                int s, d;
                if (e < N_EDGES) { s = src[e]; d = dst[e]; } else { s = e - N_EDGES; d = s; }
                int b = d >> BSH;
                int r = atomicAdd(&lcnt[b], 1);
                pv[k] = (uint32_t)s | ((uint32_t)(d & (BSIZE - 1)) << 16);
                pm[k] = (uint32_t)r | ((uint32_t)b << 16);
            }
        }
        __syncthreads();
        for (int i = threadIdx.x; i < NBUCKET; i += 256) {
            int c = lcnt[i];
            if (c) lbase[i] = atomicAdd(&bcur[i], c);
        }
        __syncthreads();
#pragma unroll
        for (int k = 0; k < T; k++) {
            int e = base + k * 256 + threadIdx.x;
            if (e < EE) {
                int b = pm[k] >> 16, r = pm[k] & 0xFFFF;
                binned[((size_t)b << CSH) + lbase[b] + r] = pv[k];
            }
        }
        return;
    }
    // ---- layer-1 GEMM half: wave-uniform x-row loads (scalar-load friendly) ----
    int c = threadIdx.x & 63;
    int wv = threadIdx.x >> 6;
    float wreg[64];
#pragma unroll
    for (int k = 0; k < 64; k++) wreg[k] = W1[k * 64 + c];
    float aw = as_w[c];
    float dw = ad_w[c];
    int base = (blockIdx.x - BIN_BLOCKS) * 16 + wv * 4;
#pragma unroll
    for (int r = 0; r < 4; r++) {
        int n = base + r;
        const float4* xr4 = (const float4*)(x + (size_t)n * 64);   // uniform address per wave
        float A0 = 0.f, A1 = 0.f, A2 = 0.f, A3 = 0.f;
#pragma unroll
        for (int k4 = 0; k4 < 16; k4++) {
            float4 xv = xr4[k4];
            A0 = fmaf(xv.x, wreg[4 * k4 + 0], A0);
            A1 = fmaf(xv.y, wreg[4 * k4 + 1], A1);
            A2 = fmaf(xv.z, wreg[4 * k4 + 2], A2);
            A3 = fmaf(xv.w, wreg[4 * k4 + 3], A3);
        }
        float acc = (A0 + A1) + (A2 + A3);
        float other = __shfl_xor(acc, 1, 64);
        if (!(c & 1)) h1b[n * 32 + (c >> 1)] = packbf(acc, other);
        float asv = acc * aw;
        float adv = acc * dw;
#pragma unroll
        for (int off = 1; off < 16; off <<= 1) {
            asv += __shfl_xor(asv, off, 64);
            adv += __shfl_xor(adv, off, 64);
        }
        if ((c & 15) == 0) { as1[n * 4 + (c >> 4)] = asv; ad1[n * 4 + (c >> 4)] = adv; }
    }
}

// -------- Phase B: rank-capture counting sort -> u16 CSR src indices --------
// rowdesc[node] = off(13b) | deg(<<13);  esrc[pos] = src (u16)
__global__ __launch_bounds__(512) void kB_sort(const int* __restrict__ bcur, const uint32_t* __restrict__ binned,
                                               int* __restrict__ rowdesc, unsigned short* __restrict__ esrc) {
    int b = blockIdx.x, tid = threadIdx.x, wv = tid >> 6;
    int p0 = b << CSH;
    int L = bcur[b];
    __shared__ int cnt8[8][BSIZE];     // per-wave histograms
    __shared__ int wbase[8][BSIZE];
    __shared__ int shs[BSIZE];
    for (int i = tid; i < 8 * BSIZE; i += 512) ((int*)cnt8)[i] = 0;
    __syncthreads();

    uint32_t pv[16];
    unsigned short rk[16];
#pragma unroll
    for (int k = 0; k < 16; k++) {
        int i = tid + k * 512;
        if (i < L) {
            uint32_t v = binned[p0 + i];
            pv[k] = v;
            rk[k] = (unsigned short)atomicAdd(&cnt8[wv][(v >> 16) & (BSIZE - 1)], 1);
        }
    }
    __syncthreads();

    int tot = 0;
    if (tid < BSIZE) {
#pragma unroll
        for (int w = 0; w < 8; w++) tot += cnt8[w][tid];
        shs[tid] = tot;
    }
    __syncthreads();
    for (int off = 1; off < BSIZE; off <<= 1) {
        int t = 0;
        if (tid < BSIZE && tid >= off) t = shs[tid - off];
        __syncthreads();
        if (tid < BSIZE && tid >= off) shs[tid] += t;
        __syncthreads();
    }
    if (tid < BSIZE) {
        int excl = shs[tid] - tot;
        int node = (b << BSH) + tid;
        if (node < N_NODES) rowdesc[node] = excl | (tot << 13);
        int wb = excl;
#pragma unroll
        for (int w = 0; w < 8; w++) { wbase[w][tid] = wb; wb += cnt8[w][tid]; }
    }
    __syncthreads();

#pragma unroll
    for (int k = 0; k < 16; k++) {
        int i = tid + k * 512;
        if (i < L) {
            uint32_t v = pv[k];
            int dl = (v >> 16) & (BSIZE - 1);
            esrc[p0 + wbase[wv][dl] + (int)rk[k]] = (unsigned short)(v & 0xFFFF);
        }
    }
}

// -------- Layer 1 aggregation (inline weights) + fused L2 GEMM: 8 edges/iter --------
__global__ __launch_bounds__(256) void k_aggr1f(
    const int* __restrict__ rowdesc, const unsigned short* __restrict__ esrc,
    const float* __restrict__ as1, const float* __restrict__ ad1,
    const uint32_t* __restrict__ h1b,
    const float* __restrict__ b1, const float* __restrict__ W2,
    const float* __restrict__ as2w, const float* __restrict__ ad2w,
    float* __restrict__ h2, float* __restrict__ as2, float* __restrict__ ad2) {
    int n = blockIdx.x * 4 + (threadIdx.x >> 6);
    int lane = threadIdx.x & 63;
    int md = rowdesc[n];
    int begin = ((n >> BSH) << CSH) + (md & (CAP - 1));
    int deg = md >> 13;

    int slot = lane >> 3, cl = lane & 7;   // edge slot = slot; lane covers channels 8cl..8cl+7
    int hc = cl >> 1;                      // head of these channels
    float ad1h = ad1[n * 4 + hc];

    const uint4* h1b4 = (const uint4*)h1b;
    float a0 = 0.f, a1 = 0.f, a2 = 0.f, a3 = 0.f, a4 = 0.f, a5 = 0.f, a6 = 0.f, a7 = 0.f, dsum = 0.f;

    int iters = (deg + 7) >> 3;
#pragma unroll 4
    for (int it = 0; it < iters; it++) {
        int idx = it * 8 + slot;
        int s = esrc[begin + idx];
        float e = as1[s * 4 + hc] + ad1h;
        float w = __expf(e >= 0.f ? e : 0.2f * e);
        w = (idx < deg) ? w : 0.f;
        uint4 v = h1b4[s * 8 + cl];
        dsum += w;
        a0 += w * bflo(v.x); a1 += w * bfhi(v.x);
        a2 += w * bflo(v.y); a3 += w * bfhi(v.y);
        a4 += w * bflo(v.z); a5 += w * bfhi(v.z);
        a6 += w * bflo(v.w); a7 += w * bfhi(v.w);
    }
#pragma unroll
    for (int off = 8; off <= 32; off <<= 1) {
        a0 += __shfl_xor(a0, off, 64); a1 += __shfl_xor(a1, off, 64);
        a2 += __shfl_xor(a2, off, 64); a3 += __shfl_xor(a3, off, 64);
        a4 += __shfl_xor(a4, off, 64); a5 += __shfl_xor(a5, off, 64);
        a6 += __shfl_xor(a6, off, 64); a7 += __shfl_xor(a7, off, 64);
        dsum += __shfl_xor(dsum, off, 64);
    }
    float dinv = 1.f / dsum;               // full denom of head hc

    float4 bb0 = *(const float4*)(b1 + 8 * cl);
    float4 bb1 = *(const float4*)(b1 + 8 * cl + 4);
    float act0 = lrelu(a0 * dinv + bb0.x, 0.01f);
    float act1 = lrelu(a1 * dinv + bb0.y, 0.01f);
    float act2 = lrelu(a2 * dinv + bb0.z, 0.01f);
    float act3 = lrelu(a3 * dinv + bb0.w, 0.01f);
    float act4 = lrelu(a4 * dinv + bb1.x, 0.01f);
    float act5 = lrelu(a5 * dinv + bb1.y, 0.01f);
    float act6 = lrelu(a6 * dinv + bb1.z, 0.01f);
    float act7 = lrelu(a7 * dinv + bb1.w, 0.01f);

    // fused L2 GEMM: lane (kg, co) sums k = 16kg..16kg+15 for output channel co
    int co = lane & 15, kg = lane >> 4;
    int l0 = 2 * kg, l1 = 2 * kg + 1;
    const float* w2r = W2 + (16 * kg) * 16 + co;
    float g = 0.f;
    g = fmaf(__shfl(act0, l0, 64), w2r[0 * 16],  g);
    g = fmaf(__shfl(act1, l0, 64), w2r[1 * 16],  g);
    g = fmaf(__shfl(act2, l0, 64), w2r[2 * 16],  g);
    g = fmaf(__shfl(act3, l0, 64), w2r[3 * 16],  g);
    g = fmaf(__shfl(act4, l0, 64), w2r[4 * 16],  g);
    g = fmaf(__shfl(act5, l0, 64), w2r[5 * 16],  g);
    g = fmaf(__shfl(act6, l0, 64), w2r[6 * 16],  g);
    g = fmaf(__shfl(act7, l0, 64), w2r[7 * 16],  g);
    g = fmaf(__shfl(act0, l1, 64), w2r[8 * 16],  g);
    g = fmaf(__shfl(act1, l1, 64), w2r[9 * 16],  g);
    g = fmaf(__shfl(act2, l1, 64), w2r[10 * 16], g);
    g = fmaf(__shfl(act3, l1, 64), w2r[11 * 16], g);
    g = fmaf(__shfl(act4, l1, 64), w2r[12 * 16], g);
    g = fmaf(__shfl(act5, l1, 64), w2r[13 * 16], g);
    g = fmaf(__shfl(act6, l1, 64), w2r[14 * 16], g);
    g = fmaf(__shfl(act7, l1, 64), w2r[15 * 16], g);
    g += __shfl_xor(g, 16, 64);
    g += __shfl_xor(g, 32, 64);
    if (lane < 16) h2[n * 16 + co] = g;
    float asv = g * as2w[co];
    float adv2 = g * ad2w[co];
#pragma unroll
    for (int off = 1; off < 16; off <<= 1) {
        asv += __shfl_xor(asv, off, 64);
        adv2 += __shfl_xor(adv2, off, 64);
    }
    if (lane == 0) { as2[n] = asv; ad2[n] = adv2; }
}

// -------- Layer 2 aggregation (inline weights) + final linear: 8 edges/iter --------
__global__ __launch_bounds__(256) void k_aggr2(
    const int* __restrict__ rowdesc, const unsigned short* __restrict__ esrc,
    const float* __restrict__ as2, const float* __restrict__ ad2,
    const float* __restrict__ h2,
    const float* __restrict__ b2, const float* __restrict__ Wo,
    const float* __restrict__ bo, float* __restrict__ out) {
    int n = blockIdx.x * 4 + (threadIdx.x >> 6);
    int lane = threadIdx.x & 63;
    int md = rowdesc[n];
    int begin = ((n >> BSH) << CSH) + (md & (CAP - 1));
    int deg = md >> 13;
    float adv = ad2[n];

    int slot = lane >> 3, c2 = lane & 7;   // lane covers channels 2c2, 2c2+1
    const float2* h22 = (const float2*)h2;
    float acc0 = 0.f, acc1 = 0.f, dsum = 0.f;

    int iters = (deg + 7) >> 3;
#pragma unroll 4
    for (int it = 0; it < iters; it++) {
        int idx = it * 8 + slot;
        int s = esrc[begin + idx];
        float e = as2[s] + adv;
        float w = __expf(e >= 0.f ? e : 0.2f * e);
        w = (idx < deg) ? w : 0.f;
        float2 hv = h22[s * 8 + c2];
        acc0 += w * hv.x;
        acc1 += w * hv.y;
        dsum += w;
    }
#pragma unroll
    for (int off = 8; off <= 32; off <<= 1) {
        acc0 += __shfl_xor(acc0, off, 64);
        acc1 += __shfl_xor(acc1, off, 64);
        dsum += __shfl_xor(dsum, off, 64);
    }
    float v0 = lrelu(acc0 / dsum + b2[2 * c2], 0.01f) * Wo[2 * c2];
    float v1 = lrelu(acc1 / dsum + b2[2 * c2 + 1], 0.01f) * Wo[2 * c2 + 1];
    float y = v0 + v1;
    y += __shfl_xor(y, 1, 64);
    y += __shfl_xor(y, 2, 64);
    y += __shfl_xor(y, 4, 64);
    if (lane == 0) out[n] = y + bo[0];
}

extern "C" void kernel_launch(void* const* d_in, const int* in_sizes, int n_in,
                              void* d_out, int out_size, void* d_ws, size_t ws_size,
                              hipStream_t stream) {
    const float* x    = (const float*)d_in[0];
    const int*   ei   = (const int*)d_in[1];
    const float* W1   = (const float*)d_in[2];
    const float* as1w = (const float*)d_in[3];
    const float* ad1w = (const float*)d_in[4];
    const float* b1   = (const float*)d_in[5];
    const float* W2   = (const float*)d_in[6];
    const float* as2w = (const float*)d_in[7];
    const float* ad2w = (const float*)d_in[8];
    const float* b2   = (const float*)d_in[9];
    const float* Wo   = (const float*)d_in[10];
    const float* bo   = (const float*)d_in[11];
    float* out = (float*)d_out;

    const int* srcp = ei;
    const int* dstp = ei + N_EDGES;

    char* p = (char*)d_ws;
    auto alloc = [&](size_t bytes) -> char* {
        char* r = p;
        p += (bytes + 255) / 256 * 256;
        return r;
    };
    // layout safety for masked tail gathers (garbage s <= 65535):
    //   h2 gather reaches <=4.2MB past h2 start  -> h1b (6.4MB) follows  OK
    //   h1b gather reaches <=8.4MB past h1b start -> as1+ad1+as2+ad2+pad (~5MB)... plus
    //   esrc pad; generous 4MB tail pad appended.
    int*            bcur    = (int*)alloc((size_t)(NBUCKET + 1) * 4);
    int*            rowdesc = (int*)alloc((size_t)N_NODES * 4);
    uint32_t*       binned  = (uint32_t*)alloc((size_t)NBUCKET * CAP * 4);
    unsigned short* esrc    = (unsigned short*)alloc((size_t)NBUCKET * CAP * 2 + 256);
    float*          h2      = (float*)alloc((size_t)N_NODES * 16 * 4);
    uint32_t*       h1b     = (uint32_t*)alloc((size_t)N_NODES * 32 * 4);
    float*          as1     = (float*)alloc((size_t)N_NODES * 4 * 4);
    float*          ad1     = (float*)alloc((size_t)N_NODES * 4 * 4);
    float*          as2     = (float*)alloc((size_t)N_NODES * 4);
    float*          ad2     = (float*)alloc((size_t)N_NODES * 4);
    (void)alloc(4 * 1024 * 1024);   // safety pad for masked tail gathers

    hipMemsetAsync(bcur, 0, (size_t)(NBUCKET + 1) * 4, stream);

    k_pre<<<BIN_BLOCKS + GEMM_BLOCKS, 256, 0, stream>>>(x, W1, as1w, ad1w, h1b, as1, ad1,
                                                        srcp, dstp, bcur, binned);
    kB_sort<<<NBUCKET, 512, 0, stream>>>(bcur, binned, rowdesc, esrc);
    k_aggr1f<<<N_NODES / 4, 256, 0, stream>>>(rowdesc, esrc, as1, ad1, h1b, b1, W2, as2w, ad2w, h2, as2, ad2);
    k_aggr2<<<N_NODES / 4, 256, 0, stream>>>(rowdesc, esrc, as2, ad2, h2, b2, Wo, bo, out);
}

// Round 13
// 195.938 us; speedup vs baseline: 5.5303x; 1.0630x over previous
//
#include <hip/hip_runtime.h>
#include <hip/hip_bf16.h>
#include <cstdint>

#define N_NODES 50000
#define N_EDGES 1600000
#define EE (N_EDGES + N_NODES)
#define BSH 7
#define BSIZE 128
#define NBUCKET ((N_NODES + BSIZE - 1) >> BSH)   // 391
#define CSH 13
#define CAP 8192                                  // pow2 bucket capacity (mean fill 4224)
#define BIN_BLOCKS 403                            // ceil(EE/4096) -- one chunk per block
#define GEMM_BLOCKS 3125                          // 3125*16 == 50000

__device__ __forceinline__ float lrelu(float x, float s) { return x >= 0.f ? x : s * x; }
__device__ __forceinline__ float bflo(uint32_t v) { return __uint_as_float(v << 16); }
__device__ __forceinline__ float bfhi(uint32_t v) { return __uint_as_float(v & 0xFFFF0000u); }
__device__ __forceinline__ uint32_t packbf(float a, float b) {
    uint32_t ua = __float_as_uint(a), ub = __float_as_uint(b);
    ua += 0x7FFF + ((ua >> 16) & 1);
    ub += 0x7FFF + ((ub >> 16) & 1);
    return (ua >> 16) | (ub & 0xFFFF0000u);
}
__device__ __forceinline__ float rdlane(float v, int l) {
    return __uint_as_float(__builtin_amdgcn_readlane(__float_as_uint(v), l));
}

// -------- Fused: edge binning (blocks 0..402, dispatched first) + layer-1 GEMM (rest) --------
__global__ __launch_bounds__(256) void k_pre(
    const float* __restrict__ x, const float* __restrict__ W1,
    const float* __restrict__ as_w, const float* __restrict__ ad_w,
    uint32_t* __restrict__ h1b, float* __restrict__ as1, float* __restrict__ ad1,
    const int* __restrict__ src, const int* __restrict__ dst,
    int* __restrict__ bcur, uint32_t* __restrict__ binned) {
    if (blockIdx.x < BIN_BLOCKS) {
        __shared__ int lcnt[NBUCKET];
        __shared__ int lbase[NBUCKET];
        const int T = 16;
        for (int i = threadIdx.x; i < NBUCKET; i += 256) lcnt[i] = 0;
        __syncthreads();
        uint32_t pv[T];
        uint32_t pm[T];
        int base = blockIdx.x * (256 * T);
        if (base + 256 * T <= N_EDGES) {
            // fast path: pure-edge chunk, int4 loads (4 edges per load)
            const int4* s4 = (const int4*)(src + base);
            const int4* d4 = (const int4*)(dst + base);
#pragma unroll
            for (int k = 0; k < 4; k++) {
                int4 sv = s4[threadIdx.x + k * 256];
                int4 dv = d4[threadIdx.x + k * 256];
                int ss[4] = {sv.x, sv.y, sv.z, sv.w};
                int dd[4] = {dv.x, dv.y, dv.z, dv.w};
#pragma unroll
                for (int j = 0; j < 4; j++) {
                    int b = dd[j] >> BSH;
                    int r = atomicAdd(&lcnt[b], 1);
                    pv[k * 4 + j] = (uint32_t)ss[j] | ((uint32_t)(dd[j] & (BSIZE - 1)) << 16);
                    pm[k * 4 + j] = (uint32_t)r | ((uint32_t)b << 16);
                }
            }
        } else {
#pragma unroll
            for (int k = 0; k < T; k++) {
                int e = base + ((k & 3) * 4 + (k >> 2)) * 256 + threadIdx.x;  // any order ok
                pm[k] = 0xFFFFFFFFu;
                if (e < EE) {
                    int s, d;
                    if (e < N_EDGES) { s = src[e]; d = dst[e]; } else { s = e - N_EDGES; d = s; }
                    int b = d >> BSH;
                    int r = atomicAdd(&lcnt[b], 1);
                    pv[k] = (uint32_t)s | ((uint32_t)(d & (BSIZE - 1)) << 16);
                    pm[k] = (uint32_t)r | ((uint32_t)b << 16);
                }
            }
        }
        __syncthreads();
        for (int i = threadIdx.x; i < NBUCKET; i += 256) {
            int c = lcnt[i];
            if (c) lbase[i] = atomicAdd(&bcur[i], c);
        }
        __syncthreads();
#pragma unroll
        for (int k = 0; k < T; k++) {
            if (pm[k] != 0xFFFFFFFFu) {
                int b = pm[k] >> 16, r = pm[k] & 0xFFFF;
                binned[((size_t)b << CSH) + lbase[b] + r] = pv[k];
            }
        }
        return;
    }
    // ---- layer-1 GEMM half: coalesced x load + readlane broadcast ----
    int c = threadIdx.x & 63;
    int wv = threadIdx.x >> 6;
    float wreg[64];
#pragma unroll
    for (int k = 0; k < 64; k++) wreg[k] = W1[k * 64 + c];
    float aw = as_w[c];
    float dw = ad_w[c];
    int base = (blockIdx.x - BIN_BLOCKS) * 16 + wv * 4;
#pragma unroll
    for (int r = 0; r < 4; r++) {
        int n = base + r;
        float xr = x[n * 64 + c];
        float a0 = 0.f, a1 = 0.f, a2 = 0.f, a3 = 0.f;
#pragma unroll
        for (int k = 0; k < 64; k += 4) {
            a0 = fmaf(rdlane(xr, k),     wreg[k],     a0);
            a1 = fmaf(rdlane(xr, k + 1), wreg[k + 1], a1);
            a2 = fmaf(rdlane(xr, k + 2), wreg[k + 2], a2);
            a3 = fmaf(rdlane(xr, k + 3), wreg[k + 3], a3);
        }
        float acc = (a0 + a1) + (a2 + a3);
        float other = __shfl_xor(acc, 1, 64);
        if (!(c & 1)) h1b[n * 32 + (c >> 1)] = packbf(acc, other);
        float asv = acc * aw;
        float adv = acc * dw;
#pragma unroll
        for (int off = 1; off < 16; off <<= 1) {
            asv += __shfl_xor(asv, off, 64);
            adv += __shfl_xor(adv, off, 64);
        }
        if ((c & 15) == 0) { as1[n * 4 + (c >> 4)] = asv; ad1[n * 4 + (c >> 4)] = adv; }
    }
}

// -------- Phase B: rank-capture counting sort -> u16 CSR src indices --------
// rowdesc[node] = off(13b) | deg(<<13);  esrc[pos] = src (u16)
__global__ __launch_bounds__(512) void kB_sort(const int* __restrict__ bcur, const uint32_t* __restrict__ binned,
                                               int* __restrict__ rowdesc, unsigned short* __restrict__ esrc) {
    int b = blockIdx.x, tid = threadIdx.x, wv = tid >> 6;
    int p0 = b << CSH;
    int L = bcur[b];
    __shared__ int cnt8[8][BSIZE];     // per-wave histograms
    __shared__ int wbase[8][BSIZE];
    __shared__ int shs[BSIZE];
    for (int i = tid; i < 8 * BSIZE; i += 512) ((int*)cnt8)[i] = 0;
    __syncthreads();

    uint32_t pv[16];
    unsigned short rk[16];
#pragma unroll
    for (int k = 0; k < 16; k++) {
        int i = tid + k * 512;
        if (i < L) {
            uint32_t v = binned[p0 + i];
            pv[k] = v;
            rk[k] = (unsigned short)atomicAdd(&cnt8[wv][(v >> 16) & (BSIZE - 1)], 1);
        }
    }
    __syncthreads();

    int tot = 0;
    if (tid < BSIZE) {
#pragma unroll
        for (int w = 0; w < 8; w++) tot += cnt8[w][tid];
        shs[tid] = tot;
    }
    __syncthreads();
    for (int off = 1; off < BSIZE; off <<= 1) {
        int t = 0;
        if (tid < BSIZE && tid >= off) t = shs[tid - off];
        __syncthreads();
        if (tid < BSIZE && tid >= off) shs[tid] += t;
        __syncthreads();
    }
    if (tid < BSIZE) {
        int excl = shs[tid] - tot;
        int node = (b << BSH) + tid;
        if (node < N_NODES) rowdesc[node] = excl | (tot << 13);
        int wb = excl;
#pragma unroll
        for (int w = 0; w < 8; w++) { wbase[w][tid] = wb; wb += cnt8[w][tid]; }
    }
    __syncthreads();

#pragma unroll
    for (int k = 0; k < 16; k++) {
        int i = tid + k * 512;
        if (i < L) {
            uint32_t v = pv[k];
            int dl = (v >> 16) & (BSIZE - 1);
            esrc[p0 + wbase[wv][dl] + (int)rk[k]] = (unsigned short)(v & 0xFFFF);
        }
    }
}

// -------- Layer 1 aggregation (inline weights) + fused L2 GEMM: 8 edges/iter --------
__global__ __launch_bounds__(256) void k_aggr1f(
    const int* __restrict__ rowdesc, const unsigned short* __restrict__ esrc,
    const float* __restrict__ as1, const float* __restrict__ ad1,
    const uint32_t* __restrict__ h1b,
    const float* __restrict__ b1, const float* __restrict__ W2,
    const float* __restrict__ as2w, const float* __restrict__ ad2w,
    float* __restrict__ h2, float* __restrict__ as2, float* __restrict__ ad2) {
    int n = blockIdx.x * 4 + (threadIdx.x >> 6);
    int lane = threadIdx.x & 63;
    int md = rowdesc[n];
    int begin = ((n >> BSH) << CSH) + (md & (CAP - 1));
    int deg = md >> 13;

    int slot = lane >> 3, cl = lane & 7;   // edge slot = slot; lane covers channels 8cl..8cl+7
    int hc = cl >> 1;                      // head of these channels
    float ad1h = ad1[n * 4 + hc];

    const uint4* h1b4 = (const uint4*)h1b;
    float a0 = 0.f, a1 = 0.f, a2 = 0.f, a3 = 0.f, a4 = 0.f, a5 = 0.f, a6 = 0.f, a7 = 0.f, dsum = 0.f;

    int iters = (deg + 7) >> 3;
#pragma unroll 4
    for (int it = 0; it < iters; it++) {
        int idx = it * 8 + slot;
        int s = esrc[begin + idx];
        float e = as1[s * 4 + hc] + ad1h;
        float w = __expf(e >= 0.f ? e : 0.2f * e);
        w = (idx < deg) ? w : 0.f;
        uint4 v = h1b4[s * 8 + cl];
        dsum += w;
        a0 += w * bflo(v.x); a1 += w * bfhi(v.x);
        a2 += w * bflo(v.y); a3 += w * bfhi(v.y);
        a4 += w * bflo(v.z); a5 += w * bfhi(v.z);
        a6 += w * bflo(v.w); a7 += w * bfhi(v.w);
    }
#pragma unroll
    for (int off = 8; off <= 32; off <<= 1) {
        a0 += __shfl_xor(a0, off, 64); a1 += __shfl_xor(a1, off, 64);
        a2 += __shfl_xor(a2, off, 64); a3 += __shfl_xor(a3, off, 64);
        a4 += __shfl_xor(a4, off, 64); a5 += __shfl_xor(a5, off, 64);
        a6 += __shfl_xor(a6, off, 64); a7 += __shfl_xor(a7, off, 64);
        dsum += __shfl_xor(dsum, off, 64);
    }
    float dinv = 1.f / dsum;               // full denom of head hc

    float4 bb0 = *(const float4*)(b1 + 8 * cl);
    float4 bb1 = *(const float4*)(b1 + 8 * cl + 4);
    float act0 = lrelu(a0 * dinv + bb0.x, 0.01f);
    float act1 = lrelu(a1 * dinv + bb0.y, 0.01f);
    float act2 = lrelu(a2 * dinv + bb0.z, 0.01f);
    float act3 = lrelu(a3 * dinv + bb0.w, 0.01f);
    float act4 = lrelu(a4 * dinv + bb1.x, 0.01f);
    float act5 = lrelu(a5 * dinv + bb1.y, 0.01f);
    float act6 = lrelu(a6 * dinv + bb1.z, 0.01f);
    float act7 = lrelu(a7 * dinv + bb1.w, 0.01f);

    // fused L2 GEMM: lane (kg, co) sums k = 16kg..16kg+15 for output channel co
    int co = lane & 15, kg = lane >> 4;
    int l0 = 2 * kg, l1 = 2 * kg + 1;
    const float* w2r = W2 + (16 * kg) * 16 + co;
    float g = 0.f;
    g = fmaf(__shfl(act0, l0, 64), w2r[0 * 16],  g);
    g = fmaf(__shfl(act1, l0, 64), w2r[1 * 16],  g);
    g = fmaf(__shfl(act2, l0, 64), w2r[2 * 16],  g);
    g = fmaf(__shfl(act3, l0, 64), w2r[3 * 16],  g);
    g = fmaf(__shfl(act4, l0, 64), w2r[4 * 16],  g);
    g = fmaf(__shfl(act5, l0, 64), w2r[5 * 16],  g);
    g = fmaf(__shfl(act6, l0, 64), w2r[6 * 16],  g);
    g = fmaf(__shfl(act7, l0, 64), w2r[7 * 16],  g);
    g = fmaf(__shfl(act0, l1, 64), w2r[8 * 16],  g);
    g = fmaf(__shfl(act1, l1, 64), w2r[9 * 16],  g);
    g = fmaf(__shfl(act2, l1, 64), w2r[10 * 16], g);
    g = fmaf(__shfl(act3, l1, 64), w2r[11 * 16], g);
    g = fmaf(__shfl(act4, l1, 64), w2r[12 * 16], g);
    g = fmaf(__shfl(act5, l1, 64), w2r[13 * 16], g);
    g = fmaf(__shfl(act6, l1, 64), w2r[14 * 16], g);
    g = fmaf(__shfl(act7, l1, 64), w2r[15 * 16], g);
    g += __shfl_xor(g, 16, 64);
    g += __shfl_xor(g, 32, 64);
    if (lane < 16) h2[n * 16 + co] = g;
    float asv = g * as2w[co];
    float adv2 = g * ad2w[co];
#pragma unroll
    for (int off = 1; off < 16; off <<= 1) {
        asv += __shfl_xor(asv, off, 64);
        adv2 += __shfl_xor(adv2, off, 64);
    }
    if (lane == 0) { as2[n] = asv; ad2[n] = adv2; }
}

// -------- Layer 2 aggregation (inline weights) + final linear: 8 edges/iter --------
__global__ __launch_bounds__(256) void k_aggr2(
    const int* __restrict__ rowdesc, const unsigned short* __restrict__ esrc,
    const float* __restrict__ as2, const float* __restrict__ ad2,
    const float* __restrict__ h2,
    const float* __restrict__ b2, const float* __restrict__ Wo,
    const float* __restrict__ bo, float* __restrict__ out) {
    int n = blockIdx.x * 4 + (threadIdx.x >> 6);
    int lane = threadIdx.x & 63;
    int md = rowdesc[n];
    int begin = ((n >> BSH) << CSH) + (md & (CAP - 1));
    int deg = md >> 13;
    float adv = ad2[n];

    int slot = lane >> 3, c2 = lane & 7;   // lane covers channels 2c2, 2c2+1
    const float2* h22 = (const float2*)h2;
    float acc0 = 0.f, acc1 = 0.f, dsum = 0.f;

    int iters = (deg + 7) >> 3;
#pragma unroll 4
    for (int it = 0; it < iters; it++) {
        int idx = it * 8 + slot;
        int s = esrc[begin + idx];
        float e = as2[s] + adv;
        float w = __expf(e >= 0.f ? e : 0.2f * e);
        w = (idx < deg) ? w : 0.f;
        float2 hv = h22[s * 8 + c2];
        acc0 += w * hv.x;
        acc1 += w * hv.y;
        dsum += w;
    }
#pragma unroll
    for (int off = 8; off <= 32; off <<= 1) {
        acc0 += __shfl_xor(acc0, off, 64);
        acc1 += __shfl_xor(acc1, off, 64);
        dsum += __shfl_xor(dsum, off, 64);
    }
    float v0 = lrelu(acc0 / dsum + b2[2 * c2], 0.01f) * Wo[2 * c2];
    float v1 = lrelu(acc1 / dsum + b2[2 * c2 + 1], 0.01f) * Wo[2 * c2 + 1];
    float y = v0 + v1;
    y += __shfl_xor(y, 1, 64);
    y += __shfl_xor(y, 2, 64);
    y += __shfl_xor(y, 4, 64);
    if (lane == 0) out[n] = y + bo[0];
}

extern "C" void kernel_launch(void* const* d_in, const int* in_sizes, int n_in,
                              void* d_out, int out_size, void* d_ws, size_t ws_size,
                              hipStream_t stream) {
    const float* x    = (const float*)d_in[0];
    const int*   ei   = (const int*)d_in[1];
    const float* W1   = (const float*)d_in[2];
    const float* as1w = (const float*)d_in[3];
    const float* ad1w = (const float*)d_in[4];
    const float* b1   = (const float*)d_in[5];
    const float* W2   = (const float*)d_in[6];
    const float* as2w = (const float*)d_in[7];
    const float* ad2w = (const float*)d_in[8];
    const float* b2   = (const float*)d_in[9];
    const float* Wo   = (const float*)d_in[10];
    const float* bo   = (const float*)d_in[11];
    float* out = (float*)d_out;

    const int* srcp = ei;
    const int* dstp = ei + N_EDGES;

    char* p = (char*)d_ws;
    auto alloc = [&](size_t bytes) -> char* {
        char* r = p;
        p += (bytes + 255) / 256 * 256;
        return r;
    };
    // layout safety for masked tail gathers (garbage s <= 65535):
    //   h2 gather reaches <=4.2MB past h2 start  -> h1b (6.4MB) follows  OK
    //   h1b gather reaches <=8.4MB past h1b start -> as1/ad1/as2/ad2 + 4MB pad follow  OK
    int*            bcur    = (int*)alloc((size_t)(NBUCKET + 1) * 4);
    int*            rowdesc = (int*)alloc((size_t)N_NODES * 4);
    uint32_t*       binned  = (uint32_t*)alloc((size_t)NBUCKET * CAP * 4);
    unsigned short* esrc    = (unsigned short*)alloc((size_t)NBUCKET * CAP * 2 + 256);
    float*          h2      = (float*)alloc((size_t)N_NODES * 16 * 4);
    uint32_t*       h1b     = (uint32_t*)alloc((size_t)N_NODES * 32 * 4);
    float*          as1     = (float*)alloc((size_t)N_NODES * 4 * 4);
    float*          ad1     = (float*)alloc((size_t)N_NODES * 4 * 4);
    float*          as2     = (float*)alloc((size_t)N_NODES * 4);
    float*          ad2     = (float*)alloc((size_t)N_NODES * 4);
    (void)alloc(4 * 1024 * 1024);   // safety pad for masked tail gathers

    hipMemsetAsync(bcur, 0, (size_t)(NBUCKET + 1) * 4, stream);

    k_pre<<<BIN_BLOCKS + GEMM_BLOCKS, 256, 0, stream>>>(x, W1, as1w, ad1w, h1b, as1, ad1,
                                                        srcp, dstp, bcur, binned);
    kB_sort<<<NBUCKET, 512, 0, stream>>>(bcur, binned, rowdesc, esrc);
    k_aggr1f<<<N_NODES / 4, 256, 0, stream>>>(rowdesc, esrc, as1, ad1, h1b, b1, W2, as2w, ad2w, h2, as2, ad2);
    k_aggr2<<<N_NODES / 4, 256, 0, stream>>>(rowdesc, esrc, as2, ad2, h2, b2, Wo, bo, out);
}